// Round 8
// baseline (357.308 us; speedup 1.0000x reference)
//
#include <hip/hip_runtime.h>

#define IN_C  128
#define HID_C 128
#define OUT_C 64
#define NPB      128      // nodes per bucket (pow2)
#define NPB_SH   7
#define NPB_MASK 127
#define MAXB     2048     // max buckets in LDS fast path (N <= 262144)
#define CAP      8192     // in-LDS sort capacity (padded bucket size), 32 KB
#define B1_CHUNK 4096     // edges per pass-1 block
#define PADQ     16       // per-node edge list padded to multiple of 16
#define PADSLACK ((PADQ - 1) * NPB)   // max padding per bucket

typedef __attribute__((ext_vector_type(8))) short short8;
typedef __attribute__((ext_vector_type(4))) float f32x4;

__device__ __forceinline__ unsigned short f2bf(float f) {
    unsigned u = __float_as_uint(f);
    unsigned r = (u + 0x7FFFu + ((u >> 16) & 1u)) >> 16;
    return (unsigned short)r;
}
__device__ __forceinline__ float bf_lo(unsigned u) { return __uint_as_float(u << 16); }
__device__ __forceinline__ float bf_hi(unsigned u) { return __uint_as_float(u & 0xFFFF0000u); }

// ---- CSR build (unchanged from round-7 passing version) --------------------

__global__ __launch_bounds__(256) void hist_kernel(const int* __restrict__ dst,
                                                   int* __restrict__ bhist,
                                                   int E, int B) {
    __shared__ int lh[MAXB];
    int t = threadIdx.x;
    int e0 = blockIdx.x * B1_CHUNK;
    int nE = min(B1_CHUNK, E - e0);
    if (B <= MAXB) {
        for (int i = t; i < B; i += 256) lh[i] = 0;
        __syncthreads();
        for (int i = t; i < nE; i += 256) atomicAdd(&lh[dst[e0 + i] >> NPB_SH], 1);
        __syncthreads();
        for (int i = t; i < B; i += 256)
            if (lh[i]) atomicAdd(&bhist[i], lh[i]);
    } else {
        for (int i = t; i < nE; i += 256) atomicAdd(&bhist[dst[e0 + i] >> NPB_SH], 1);
    }
}

// bbase[i] = true exclusive prefix; bcur[i] = padded region base
__global__ __launch_bounds__(1024) void scan_bucket_kernel(const int* __restrict__ bhist,
                                                           int* __restrict__ bbase,
                                                           int* __restrict__ bcur, int B) {
    __shared__ int sums[1024];
    int t = threadIdx.x;
    int chunk = (B + 1023) >> 10;
    int beg = t * chunk, end = min(beg + chunk, B);
    int s = 0;
    for (int i = beg; i < end; ++i) s += bhist[i];
    sums[t] = s;
    __syncthreads();
    for (int off = 1; off < 1024; off <<= 1) {
        int v = (t >= off) ? sums[t - off] : 0;
        __syncthreads();
        sums[t] += v;
        __syncthreads();
    }
    int run = (t == 0) ? 0 : sums[t - 1];
    for (int i = beg; i < end; ++i) {
        bbase[i] = run;
        bcur[i] = run + i * PADSLACK;     // padded scatter base
        run += bhist[i];
    }
    if (t == 1023) bbase[B] = sums[1023];
}

__global__ __launch_bounds__(256) void bucket_kernel(const int* __restrict__ src,
                                                     const int* __restrict__ dst,
                                                     int* __restrict__ bcur,
                                                     int* __restrict__ col,
                                                     int E, int B) {
    __shared__ int hist[MAXB];
    __shared__ int runb[MAXB];
    int t = threadIdx.x;
    int e0 = blockIdx.x * B1_CHUNK;
    int nE = min(B1_CHUNK, E - e0);
    if (B <= MAXB) {
        for (int i = t; i < B; i += 256) hist[i] = 0;
        __syncthreads();
        for (int i = t; i < nE; i += 256) atomicAdd(&hist[dst[e0 + i] >> NPB_SH], 1);
        __syncthreads();
        for (int i = t; i < B; i += 256) {
            int c = hist[i];
            runb[i] = c ? atomicAdd(&bcur[i], c) : 0;
            hist[i] = 0;
        }
        __syncthreads();
        for (int i = t; i < nE; i += 256) {
            int d = dst[e0 + i], s = src[e0 + i];
            int b = d >> NPB_SH;
            int off2 = atomicAdd(&hist[b], 1);
            col[runb[b] + off2] = (s << NPB_SH) | (d & NPB_MASK);
        }
    } else {
        for (int i = t; i < nE; i += 256) {
            int d = dst[e0 + i], s = src[e0 + i];
            int pos = atomicAdd(&bcur[d >> NPB_SH], 1);
            col[pos] = (s << NPB_SH) | (d & NPB_MASK);
        }
    }
}

__global__ __launch_bounds__(256) void csr_kernel(int* __restrict__ col,
                                                  const int* __restrict__ bbase,
                                                  int* __restrict__ rowptr,
                                                  int* __restrict__ rowend,
                                                  float* __restrict__ dinv,
                                                  int N, int E) {
    __shared__ int sorted[CAP];
    __shared__ int lhist[NPB];
    __shared__ int lpre[NPB + 1];
    int b = blockIdx.x;
    int t = threadIdx.x;
    int size = bbase[b + 1] - bbase[b];
    int pbase = bbase[b] + b * PADSLACK;      // bucket region base in col
    int node_base = b << NPB_SH;
    int nn = min(NPB, N - node_base);

    if (t < NPB) lhist[t] = 0;
    __syncthreads();
    for (int i = t; i < size; i += 256) atomicAdd(&lhist[col[pbase + i] & NPB_MASK], 1);
    __syncthreads();
    // padded per-node counts -> inclusive prefix in lpre[1..NPB]
    if (t < NPB) lpre[t + 1] = (lhist[t] + PADQ - 1) & ~(PADQ - 1);
    if (t == 0) lpre[0] = 0;
    __syncthreads();
    for (int off = 1; off < NPB; off <<= 1) {
        int v = (t >= off && t < NPB) ? lpre[t + 1 - off] : 0;
        __syncthreads();
        if (t < NPB) lpre[t + 1] += v;
        __syncthreads();
    }
    if (t < nn) {
        rowptr[node_base + t] = pbase + lpre[t];
        rowend[node_base + t] = pbase + lpre[t + 1];   // own pads only
        dinv[node_base + t] = rsqrtf((float)(lhist[t] + 1));
    }
    if (t < NPB) lhist[t] = lpre[t];
    __syncthreads();
    int psize = lpre[NPB];
    if (psize <= CAP) {
        // in-LDS counting sort with sentinel pads, then in-place write-back
        for (int i = t; i < psize; i += 256) sorted[i] = N;
        __syncthreads();
        for (int i = t; i < size; i += 256) {
            int entry = col[pbase + i];
            int slot = atomicAdd(&lhist[entry & NPB_MASK], 1);
            sorted[slot] = entry >> NPB_SH;
        }
        __syncthreads();
        for (int i = t; i < psize; i += 256) col[pbase + i] = sorted[i];
    } else {
        // fallback (dead for this dataset: psize ~3000): register staging
        int ent[32];
        int c2 = 0;
        for (int i = t; i < size && c2 < 32; i += 256) ent[c2++] = col[pbase + i];
        __syncthreads();
        for (int i = t; i < psize; i += 256) col[pbase + i] = N;
        __syncthreads();
        c2 = 0;
        for (int i = t; i < size && c2 < 32; i += 256) {
            int entry = ent[c2++];
            int slot = atomicAdd(&lhist[entry & NPB_MASK], 1);
            col[pbase + slot] = entry >> NPB_SH;
        }
    }
}

// ---- MFMA dense transform (row-major H [n+1][C]; row n kept zero) ----------

template<int C, typename InT>
__global__ __launch_bounds__(256) void mm_mfma_kernel(
    const InT* __restrict__ X, const float* __restrict__ W,
    const float* __restrict__ dinv, unsigned short* __restrict__ Hs, int n) {
    constexpr int LD = 136;
    __shared__ unsigned short Wt[C][LD];
    int t = threadIdx.x;

    if (blockIdx.x == 0) {   // zero sentinel row n (gather target for pads)
        for (int i = t; i < C / 2; i += 256)
            ((unsigned*)(Hs + (size_t)n * C))[i] = 0;
    }

    for (int i = t; i < (128 * C) / 4; i += 256) {
        int idx = i * 4;
        int k = idx / C, c = idx % C;
        float4 wv = *(const float4*)&W[(size_t)k * C + c];
        Wt[c + 0][k] = f2bf(wv.x);
        Wt[c + 1][k] = f2bf(wv.y);
        Wt[c + 2][k] = f2bf(wv.z);
        Wt[c + 3][k] = f2bf(wv.w);
    }
    __syncthreads();

    int w = t >> 6, lane = t & 63;
    int m = lane & 15, quad = lane >> 4;
    int row0 = blockIdx.x * 64 + w * 16;
    int arow = min(row0 + m, n - 1);

    constexpr int NT = C / 16;
    f32x4 acc[NT];
#pragma unroll
    for (int ct = 0; ct < NT; ++ct) acc[ct] = (f32x4){0.f, 0.f, 0.f, 0.f};

#pragma unroll
    for (int kk = 0; kk < 4; ++kk) {
        int k0 = kk * 32 + quad * 8;
        short8 a;
        if constexpr (sizeof(InT) == 4) {
            const float* xp = (const float*)X + (size_t)arow * 128 + k0;
            float4 f0 = *(const float4*)xp;
            float4 f1 = *(const float4*)(xp + 4);
            a[0] = (short)f2bf(f0.x); a[1] = (short)f2bf(f0.y);
            a[2] = (short)f2bf(f0.z); a[3] = (short)f2bf(f0.w);
            a[4] = (short)f2bf(f1.x); a[5] = (short)f2bf(f1.y);
            a[6] = (short)f2bf(f1.z); a[7] = (short)f2bf(f1.w);
        } else {
            a = *(const short8*)((const unsigned short*)X + (size_t)arow * 128 + k0);
        }
#pragma unroll
        for (int ct = 0; ct < NT; ++ct) {
            short8 b = *(const short8*)&Wt[ct * 16 + m][k0];
            acc[ct] = __builtin_amdgcn_mfma_f32_16x16x32_bf16(a, b, acc[ct], 0, 0, 0);
        }
    }

    int qrow = row0 + quad * 4;
    float dv[4];
#pragma unroll
    for (int r = 0; r < 4; ++r) dv[r] = (qrow + r < n) ? dinv[qrow + r] : 0.f;
#pragma unroll
    for (int ct = 0; ct < NT; ++ct) {
        int c = ct * 16 + m;
#pragma unroll
        for (int r = 0; r < 4; ++r) {
            int row = qrow + r;
            if (row < n) Hs[(size_t)row * C + c] = f2bf(acc[ct][r] * dv[r]);
        }
    }
}

// ---- aggregation: out[d] = dinv[d]*(Hs[d] + sum_{s in N(d)} Hs[s]) + b -----
// MULTI-NODE PIPELINED wave: each wave owns NPN nodes. All NPN rowptr/rowend
// (scalar), self-rows, and first-batch col loads issue as independent
// round-trips; the gather loop interleaves issue across nodes in lockstep
// (NPN*U uint4 loads in flight vs 4 before). This attacks the measured
// latency wall: layer1 (409MB) and layer2 (205MB) both took 81.5us in the
// single-node version -> per-node serial RT chain, not bandwidth, was the
// limit. Edge lists padded to PADQ=16 with sentinel N (zero row), so trip
// counts are exact; shuffle sources always e < cnt (guarded by groups).
// Over-reads of col (inactive node, lockstep j0) land in neighbor regions /
// H1 -- mapped workspace, values never used as addresses.

template<int C, bool BOUT, int NPN>
__global__ __launch_bounds__(256) void agg_kernel(
    const unsigned short* __restrict__ Hs, const float* __restrict__ bias,
    const float* __restrict__ dinv, const int* __restrict__ rowptr,
    const int* __restrict__ rowend, const int* __restrict__ col,
    void* __restrict__ outv, int n, int relu) {
    constexpr int LPR = C / 8;          // lanes per row
    constexpr int SLOTS = 64 / LPR;     // rows gathered per wave-load
    constexpr int U = (SLOTS == 4) ? 4 : 2;   // issue unit; groups % U == 0
    int wid = (blockIdx.x * 256 + threadIdx.x) >> 6;
    int d0 = wid * NPN;
    if (d0 >= n) return;
    int lane = threadIdx.x & 63;
    int cl = lane & (LPR - 1);
    int slot = lane / LPR;

    // front-loaded independent round-trips for all NPN nodes
    int beg[NPN], len[NPN];
    float dv[NPN];
    uint4 sv[NPN];
#pragma unroll
    for (int k = 0; k < NPN; ++k) {
        int d = d0 + k;
        int dd = min(d, n - 1);
        beg[k] = rowptr[dd];
        len[k] = (d < n) ? (rowend[dd] - beg[k]) : 0;
        dv[k] = dinv[dd];
        sv[k] = *((const uint4*)(Hs + (size_t)dd * C) + cl);   // self row
    }

    float acc[NPN][8];
#pragma unroll
    for (int k = 0; k < NPN; ++k)
#pragma unroll
        for (int q = 0; q < 8; ++q) acc[k][q] = 0.f;

    int lmax = 0;
#pragma unroll
    for (int k = 0; k < NPN; ++k) lmax = max(lmax, len[k]);

    for (int j0 = 0; j0 < lmax; j0 += 64) {
        int colv[NPN], groups[NPN];
#pragma unroll
        for (int k = 0; k < NPN; ++k)
            colv[k] = __builtin_nontemporal_load(col + beg[k] + j0 + lane);
#pragma unroll
        for (int k = 0; k < NPN; ++k) {
            int c = len[k] - j0;
            c = c < 0 ? 0 : (c > 64 ? 64 : c);   // multiple of 16
            groups[k] = c / SLOTS;               // multiple of U
        }
        int gmax = 0;
#pragma unroll
        for (int k = 0; k < NPN; ++k) gmax = max(gmax, groups[k]);
        for (int g = 0; g < gmax; g += U) {
            uint4 v[NPN][U];
            // issue phase: NPN*U independent gathers in flight
#pragma unroll
            for (int k = 0; k < NPN; ++k) {
                if (g < groups[k]) {
#pragma unroll
                    for (int b = 0; b < U; ++b) {
                        int e = (g + b) * SLOTS + slot;      // e < cnt guaranteed
                        int idx = __shfl(colv[k], e, 64);
                        v[k][b] = *((const uint4*)(Hs + (size_t)idx * C) + cl);
                    }
                }
            }
            // consume phase
#pragma unroll
            for (int k = 0; k < NPN; ++k) {
                if (g < groups[k]) {
#pragma unroll
                    for (int b = 0; b < U; ++b) {
                        acc[k][0] += bf_lo(v[k][b].x); acc[k][1] += bf_hi(v[k][b].x);
                        acc[k][2] += bf_lo(v[k][b].y); acc[k][3] += bf_hi(v[k][b].y);
                        acc[k][4] += bf_lo(v[k][b].z); acc[k][5] += bf_hi(v[k][b].z);
                        acc[k][6] += bf_lo(v[k][b].w); acc[k][7] += bf_hi(v[k][b].w);
                    }
                }
            }
        }
    }

    float4 b0 = *((const float4*)bias + cl * 2);
    float4 b1 = *((const float4*)bias + cl * 2 + 1);
#pragma unroll
    for (int k = 0; k < NPN; ++k) {
        int d = d0 + k;
        if (d >= n) break;
#pragma unroll
        for (int mk = LPR; mk < 64; mk <<= 1) {
#pragma unroll
            for (int q = 0; q < 8; ++q) acc[k][q] += __shfl_xor(acc[k][q], mk, 64);
        }
        acc[k][0] += bf_lo(sv[k].x); acc[k][1] += bf_hi(sv[k].x);
        acc[k][2] += bf_lo(sv[k].y); acc[k][3] += bf_hi(sv[k].y);
        acc[k][4] += bf_lo(sv[k].z); acc[k][5] += bf_hi(sv[k].z);
        acc[k][6] += bf_lo(sv[k].w); acc[k][7] += bf_hi(sv[k].w);
        float r[8];
        r[0] = dv[k] * acc[k][0] + b0.x; r[1] = dv[k] * acc[k][1] + b0.y;
        r[2] = dv[k] * acc[k][2] + b0.z; r[3] = dv[k] * acc[k][3] + b0.w;
        r[4] = dv[k] * acc[k][4] + b1.x; r[5] = dv[k] * acc[k][5] + b1.y;
        r[6] = dv[k] * acc[k][6] + b1.z; r[7] = dv[k] * acc[k][7] + b1.w;
        if (relu) {
#pragma unroll
            for (int q = 0; q < 8; ++q) r[q] = fmaxf(r[q], 0.f);
        }
        if (slot == 0) {
            if constexpr (BOUT) {
                uint4 o;
                o.x = (unsigned)f2bf(r[0]) | ((unsigned)f2bf(r[1]) << 16);
                o.y = (unsigned)f2bf(r[2]) | ((unsigned)f2bf(r[3]) << 16);
                o.z = (unsigned)f2bf(r[4]) | ((unsigned)f2bf(r[5]) << 16);
                o.w = (unsigned)f2bf(r[6]) | ((unsigned)f2bf(r[7]) << 16);
                *(uint4*)((unsigned short*)outv + (size_t)d * C + cl * 8) = o;
            } else {
                float* o = (float*)outv + (size_t)d * C + cl * 8;
                *(float4*)o = make_float4(r[0], r[1], r[2], r[3]);
                *(float4*)(o + 4) = make_float4(r[4], r[5], r[6], r[7]);
            }
        }
    }
}

// ---- driver ----------------------------------------------------------------

extern "C" void kernel_launch(void* const* d_in, const int* in_sizes, int n_in,
                              void* d_out, int out_size, void* d_ws, size_t ws_size,
                              hipStream_t stream) {
    const float* x  = (const float*)d_in[0];
    const int*   ei = (const int*)d_in[1];
    const float* W1 = (const float*)d_in[2];
    const float* b1 = (const float*)d_in[3];
    const float* W2 = (const float*)d_in[4];
    const float* b2 = (const float*)d_in[5];
    float* out = (float*)d_out;

    int N = in_sizes[0] / IN_C;
    int E = in_sizes[1] / 2;
    const int* src = ei;
    const int* dst = ei + E;
    int B = (N + NPB - 1) >> NPB_SH;
    int nblk = (E + B1_CHUNK - 1) / B1_CHUNK;

    // workspace ≈ 64.8 MB for N=100k, E=1.6M (same scale as proven baseline)
    char* ws = (char*)d_ws;
    size_t off = 0;
    int*   bhist  = (int*)(ws + off);   off += (size_t)B * 4;
    int*   bbase  = (int*)(ws + off);   off += (size_t)(B + 1) * 4;
    int*   bcur   = (int*)(ws + off);   off += (size_t)B * 4;
    float* dinv   = (float*)(ws + off); off += (size_t)N * 4;
    int*   rowptr = (int*)(ws + off);   off += (size_t)N * 4;
    int*   rowend = (int*)(ws + off);   off += (size_t)N * 4;
    off = (off + 15) & ~(size_t)15;
    int*   col    = (int*)(ws + off);   off += ((size_t)E + (size_t)B * PADSLACK + 64) * 4;
    off = (off + 15) & ~(size_t)15;
    unsigned short* H1  = (unsigned short*)(ws + off); off += (size_t)(N + 1) * HID_C * 2;
    off = (off + 15) & ~(size_t)15;
    unsigned short* AG1 = (unsigned short*)(ws + off); off += (size_t)N * HID_C * 2;
    unsigned short* H2 = H1;   // reuse; sentinel row N fits ((N+1)*64 <= (N+1)*128)

    hipMemsetAsync(bhist, 0, (size_t)B * 4, stream);

    hist_kernel<<<nblk, 256, 0, stream>>>(dst, bhist, E, B);
    scan_bucket_kernel<<<1, 1024, 0, stream>>>(bhist, bbase, bcur, B);
    bucket_kernel<<<nblk, 256, 0, stream>>>(src, dst, bcur, col, E, B);
    csr_kernel<<<B, 256, 0, stream>>>(col, bbase, rowptr, rowend, dinv, N, E);

    int mblk = (N + 63) / 64;
    mm_mfma_kernel<HID_C, float><<<mblk, 256, 0, stream>>>(x, W1, dinv, H1, N);
    // NPN=2 nodes/wave (C=128): 8 nodes per 256-thr block
    agg_kernel<HID_C, true, 2><<<(N + 7) / 8, 256, 0, stream>>>(
        H1, b1, dinv, rowptr, rowend, col, AG1, N, 1);

    mm_mfma_kernel<OUT_C, unsigned short><<<mblk, 256, 0, stream>>>(AG1, W2, dinv, H2, N);
    // NPN=4 nodes/wave (C=64): 16 nodes per 256-thr block
    agg_kernel<OUT_C, false, 4><<<(N + 15) / 16, 256, 0, stream>>>(
        H2, b2, dinv, rowptr, rowend, col, out, N, 0);
}

// Round 9
// 342.806 us; speedup vs baseline: 1.0423x; 1.0423x over previous
//
#include <hip/hip_runtime.h>

#define IN_C  128
#define HID_C 128
#define OUT_C 64
#define NPB      128      // nodes per bucket (pow2)
#define NPB_SH   7
#define NPB_MASK 127
#define MAXB     2048     // max buckets in LDS fast path (N <= 262144)
#define CAP      8192     // in-LDS sort capacity (padded bucket size), 32 KB
#define B1_CHUNK 4096     // edges per pass-1 block
#define PADQ     16       // per-node edge list padded to multiple of 16
#define PADSLACK ((PADQ - 1) * NPB)   // max padding per bucket

typedef __attribute__((ext_vector_type(8))) short short8;
typedef __attribute__((ext_vector_type(4))) float f32x4;

__device__ __forceinline__ unsigned short f2bf(float f) {
    unsigned u = __float_as_uint(f);
    unsigned r = (u + 0x7FFFu + ((u >> 16) & 1u)) >> 16;
    return (unsigned short)r;
}
__device__ __forceinline__ float bf_lo(unsigned u) { return __uint_as_float(u << 16); }
__device__ __forceinline__ float bf_hi(unsigned u) { return __uint_as_float(u & 0xFFFF0000u); }

// ---- CSR build -------------------------------------------------------------

__global__ __launch_bounds__(256) void hist_kernel(const int* __restrict__ dst,
                                                   int* __restrict__ bhist,
                                                   int E, int B) {
    __shared__ int lh[MAXB];
    int t = threadIdx.x;
    int e0 = blockIdx.x * B1_CHUNK;
    int nE = min(B1_CHUNK, E - e0);
    if (B <= MAXB) {
        for (int i = t; i < B; i += 256) lh[i] = 0;
        __syncthreads();
        for (int i = t; i < nE; i += 256) atomicAdd(&lh[dst[e0 + i] >> NPB_SH], 1);
        __syncthreads();
        for (int i = t; i < B; i += 256)
            if (lh[i]) atomicAdd(&bhist[i], lh[i]);
    } else {
        for (int i = t; i < nE; i += 256) atomicAdd(&bhist[dst[e0 + i] >> NPB_SH], 1);
    }
}

// bbase[i] = true exclusive prefix; bcur[i] = padded region base
__global__ __launch_bounds__(1024) void scan_bucket_kernel(const int* __restrict__ bhist,
                                                           int* __restrict__ bbase,
                                                           int* __restrict__ bcur, int B) {
    __shared__ int sums[1024];
    int t = threadIdx.x;
    int chunk = (B + 1023) >> 10;
    int beg = t * chunk, end = min(beg + chunk, B);
    int s = 0;
    for (int i = beg; i < end; ++i) s += bhist[i];
    sums[t] = s;
    __syncthreads();
    for (int off = 1; off < 1024; off <<= 1) {
        int v = (t >= off) ? sums[t - off] : 0;
        __syncthreads();
        sums[t] += v;
        __syncthreads();
    }
    int run = (t == 0) ? 0 : sums[t - 1];
    for (int i = beg; i < end; ++i) {
        bbase[i] = run;
        bcur[i] = run + i * PADSLACK;     // padded scatter base
        run += bhist[i];
    }
    if (t == 1023) bbase[B] = sums[1023];
}

// LDS-staged sorted scatter: sort the block's 4096 edges by bucket in LDS,
// then write bucket-ordered runs (consecutive lanes -> consecutive global
// addresses within each run). Replaces 1.6M random 4B global writes (each a
// 64B-line RMW ~= 100MB x2 of random traffic at the ~3.7 TB/s random-line
// ceiling) with ~5x fewer line touches.
__global__ __launch_bounds__(256) void bucket_kernel(const int* __restrict__ src,
                                                     const int* __restrict__ dst,
                                                     int* __restrict__ bcur,
                                                     int* __restrict__ col,
                                                     int E, int B) {
    __shared__ int hist[MAXB];      // counts, then scatter cursor
    __shared__ int lbase[MAXB];     // local exclusive prefix
    __shared__ int gbase[MAXB];     // global run base for this block
    __shared__ int part[256];
    __shared__ int stage[B1_CHUNK];
    __shared__ short bstage[B1_CHUNK];
    int t = threadIdx.x;
    int e0 = blockIdx.x * B1_CHUNK;
    int nE = min(B1_CHUNK, E - e0);
    if (B <= MAXB) {
        for (int i = t; i < B; i += 256) hist[i] = 0;
        __syncthreads();
        for (int i = t; i < nE; i += 256) atomicAdd(&hist[dst[e0 + i] >> NPB_SH], 1);
        __syncthreads();
        // local exclusive prefix over B buckets + global base allocation
        int chunk = (B + 255) >> 8;
        int beg = t * chunk, end = min(beg + chunk, B);
        int s = 0;
        for (int i = beg; i < end; ++i) s += hist[i];
        part[t] = s;
        __syncthreads();
        for (int off = 1; off < 256; off <<= 1) {
            int v = (t >= off) ? part[t - off] : 0;
            __syncthreads();
            part[t] += v;
            __syncthreads();
        }
        int run = (t == 0) ? 0 : part[t - 1];
        for (int i = beg; i < end; ++i) {
            int c = hist[i];
            lbase[i] = run;
            gbase[i] = c ? atomicAdd(&bcur[i], c) : 0;
            run += c;
        }
        __syncthreads();
        for (int i = t; i < B; i += 256) hist[i] = lbase[i];   // cursor
        __syncthreads();
        // scatter into LDS staging, sorted by bucket
        for (int i = t; i < nE; i += 256) {
            int d = dst[e0 + i], s2 = src[e0 + i];
            int b = d >> NPB_SH;
            int slot = atomicAdd(&hist[b], 1);
            stage[slot] = (s2 << NPB_SH) | (d & NPB_MASK);
            bstage[slot] = (short)b;
        }
        __syncthreads();
        // bucket-ordered write-out: runs are contiguous in both LDS & global
        for (int i = t; i < nE; i += 256) {
            int b = bstage[i];
            col[gbase[b] + (i - lbase[b])] = stage[i];
        }
    } else {
        for (int i = t; i < nE; i += 256) {
            int d = dst[e0 + i], s = src[e0 + i];
            int pos = atomicAdd(&bcur[d >> NPB_SH], 1);
            col[pos] = (s << NPB_SH) | (d & NPB_MASK);
        }
    }
}

__global__ __launch_bounds__(256) void csr_kernel(int* __restrict__ col,
                                                  const int* __restrict__ bbase,
                                                  int* __restrict__ rowptr,
                                                  int* __restrict__ rowend,
                                                  float* __restrict__ dinv,
                                                  int N, int E) {
    __shared__ int sorted[CAP];
    __shared__ int lhist[NPB];
    __shared__ int lpre[NPB + 1];
    int b = blockIdx.x;
    int t = threadIdx.x;
    int size = bbase[b + 1] - bbase[b];
    int pbase = bbase[b] + b * PADSLACK;      // bucket region base in col
    int node_base = b << NPB_SH;
    int nn = min(NPB, N - node_base);

    if (t < NPB) lhist[t] = 0;
    __syncthreads();
    for (int i = t; i < size; i += 256) atomicAdd(&lhist[col[pbase + i] & NPB_MASK], 1);
    __syncthreads();
    // padded per-node counts -> inclusive prefix in lpre[1..NPB]
    if (t < NPB) lpre[t + 1] = (lhist[t] + PADQ - 1) & ~(PADQ - 1);
    if (t == 0) lpre[0] = 0;
    __syncthreads();
    for (int off = 1; off < NPB; off <<= 1) {
        int v = (t >= off && t < NPB) ? lpre[t + 1 - off] : 0;
        __syncthreads();
        if (t < NPB) lpre[t + 1] += v;
        __syncthreads();
    }
    if (t < nn) {
        rowptr[node_base + t] = pbase + lpre[t];
        rowend[node_base + t] = pbase + lpre[t + 1];   // own pads only
        dinv[node_base + t] = rsqrtf((float)(lhist[t] + 1));
    }
    if (t < NPB) lhist[t] = lpre[t];
    __syncthreads();
    int psize = lpre[NPB];
    if (psize <= CAP) {
        // in-LDS counting sort with sentinel pads, then in-place write-back
        for (int i = t; i < psize; i += 256) sorted[i] = N;
        __syncthreads();
        for (int i = t; i < size; i += 256) {
            int entry = col[pbase + i];
            int slot = atomicAdd(&lhist[entry & NPB_MASK], 1);
            sorted[slot] = entry >> NPB_SH;
        }
        __syncthreads();
        for (int i = t; i < psize; i += 256) col[pbase + i] = sorted[i];
    } else {
        // fallback (dead for this dataset: psize ~3000): register staging
        int ent[32];
        int c2 = 0;
        for (int i = t; i < size && c2 < 32; i += 256) ent[c2++] = col[pbase + i];
        __syncthreads();
        for (int i = t; i < psize; i += 256) col[pbase + i] = N;
        __syncthreads();
        c2 = 0;
        for (int i = t; i < size && c2 < 32; i += 256) {
            int entry = ent[c2++];
            int slot = atomicAdd(&lhist[entry & NPB_MASK], 1);
            col[pbase + slot] = entry >> NPB_SH;
        }
    }
}

// ---- W pre-convert: Wt[c][k] = bf16(W[k][c]), once per launch --------------
__global__ __launch_bounds__(256) void wcvt_kernel(const float* __restrict__ W,
                                                   unsigned short* __restrict__ Wt,
                                                   int C) {   // K fixed = 128
    int i = blockIdx.x * 256 + threadIdx.x;
    if (i >= 32 * C) return;            // 128*C/4 quads
    int idx = i * 4;
    int k = idx / C, c = idx % C;
    float4 wv = *(const float4*)&W[(size_t)k * C + c];
    Wt[(size_t)(c + 0) * 128 + k] = f2bf(wv.x);
    Wt[(size_t)(c + 1) * 128 + k] = f2bf(wv.y);
    Wt[(size_t)(c + 2) * 128 + k] = f2bf(wv.z);
    Wt[(size_t)(c + 3) * 128 + k] = f2bf(wv.w);
}

// ---- MFMA dense transform (row-major H [n+1][C]; row n kept zero) ----------
// W arrives pre-converted/transposed bf16 [C][128]: LDS fill is a straight
// 16B-vector copy (half the bytes, zero convert ALU vs fp32 W per block).

template<int C, typename InT>
__global__ __launch_bounds__(256) void mm_mfma_kernel(
    const InT* __restrict__ X, const unsigned short* __restrict__ Wpre,
    const float* __restrict__ dinv, unsigned short* __restrict__ Hs, int n) {
    constexpr int LD = 136;
    __shared__ unsigned short Wt[C][LD];
    int t = threadIdx.x;

    if (blockIdx.x == 0) {   // zero sentinel row n (gather target for pads)
        for (int i = t; i < C / 2; i += 256)
            ((unsigned*)(Hs + (size_t)n * C))[i] = 0;
    }

    for (int i = t; i < (C * 128) / 8; i += 256) {
        int idx = i * 8;
        int c = idx >> 7, k = idx & 127;
        *(short8*)&Wt[c][k] = *(const short8*)&Wpre[idx];
    }
    __syncthreads();

    int w = t >> 6, lane = t & 63;
    int m = lane & 15, quad = lane >> 4;
    int row0 = blockIdx.x * 64 + w * 16;
    int arow = min(row0 + m, n - 1);

    constexpr int NT = C / 16;
    f32x4 acc[NT];
#pragma unroll
    for (int ct = 0; ct < NT; ++ct) acc[ct] = (f32x4){0.f, 0.f, 0.f, 0.f};

#pragma unroll
    for (int kk = 0; kk < 4; ++kk) {
        int k0 = kk * 32 + quad * 8;
        short8 a;
        if constexpr (sizeof(InT) == 4) {
            const float* xp = (const float*)X + (size_t)arow * 128 + k0;
            float4 f0 = *(const float4*)xp;
            float4 f1 = *(const float4*)(xp + 4);
            a[0] = (short)f2bf(f0.x); a[1] = (short)f2bf(f0.y);
            a[2] = (short)f2bf(f0.z); a[3] = (short)f2bf(f0.w);
            a[4] = (short)f2bf(f1.x); a[5] = (short)f2bf(f1.y);
            a[6] = (short)f2bf(f1.z); a[7] = (short)f2bf(f1.w);
        } else {
            a = *(const short8*)((const unsigned short*)X + (size_t)arow * 128 + k0);
        }
#pragma unroll
        for (int ct = 0; ct < NT; ++ct) {
            short8 b = *(const short8*)&Wt[ct * 16 + m][k0];
            acc[ct] = __builtin_amdgcn_mfma_f32_16x16x32_bf16(a, b, acc[ct], 0, 0, 0);
        }
    }

    int qrow = row0 + quad * 4;
    float dv[4];
#pragma unroll
    for (int r = 0; r < 4; ++r) dv[r] = (qrow + r < n) ? dinv[qrow + r] : 0.f;
#pragma unroll
    for (int ct = 0; ct < NT; ++ct) {
        int c = ct * 16 + m;
#pragma unroll
        for (int r = 0; r < 4; ++r) {
            int row = qrow + r;
            if (row < n) Hs[(size_t)row * C + c] = f2bf(acc[ct][r] * dv[r]);
        }
    }
}

// ---- aggregation (round-7 proven version: at random-line memory roofline) --

#define GBODY(NB)                                                              \
    {                                                                          \
        uint4 v[NB];                                                           \
        _Pragma("unroll") for (int b = 0; b < NB; ++b) {                       \
            int e = (g + b) * SLOTS + slot;                                    \
            int idx = __shfl(colv, e, 64);                                     \
            v[b] = *((const uint4*)(Hs + (size_t)idx * C) + cl);               \
        }                                                                      \
        _Pragma("unroll") for (int b = 0; b < NB; ++b) {                       \
            acc[0] += bf_lo(v[b].x); acc[1] += bf_hi(v[b].x);                  \
            acc[2] += bf_lo(v[b].y); acc[3] += bf_hi(v[b].y);                  \
            acc[4] += bf_lo(v[b].z); acc[5] += bf_hi(v[b].z);                  \
            acc[6] += bf_lo(v[b].w); acc[7] += bf_hi(v[b].w);                  \
        }                                                                      \
    }

template<int C, bool BOUT>
__global__ __launch_bounds__(256) void agg_kernel(
    const unsigned short* __restrict__ Hs, const float* __restrict__ bias,
    const float* __restrict__ dinv, const int* __restrict__ rowptr,
    const int* __restrict__ rowend, const int* __restrict__ col,
    void* __restrict__ outv, int n, int relu) {
    constexpr int LPR = C / 8;        // lanes per row
    constexpr int SLOTS = 64 / LPR;   // rows gathered per wave-load
    int d = (blockIdx.x * 256 + threadIdx.x) >> 6;
    if (d >= n) return;
    int lane = threadIdx.x & 63;
    int cl = lane & (LPR - 1);
    int slot = lane / LPR;

    float acc[8] = {0.f, 0.f, 0.f, 0.f, 0.f, 0.f, 0.f, 0.f};
    int beg = rowptr[d], end = rowend[d];

    for (int j0 = beg; j0 < end; j0 += 64) {
        int cnt = min(64, end - j0);          // multiple of PADQ=16
        int colv = col[j0 + lane];            // slack-allocated: no guard
        int groups = cnt / SLOTS;
        int g = 0;
        for (; g + 4 <= groups; g += 4) GBODY(4)
        if constexpr (SLOTS == 8) {           // C=64: groups may be ≡2 mod 4
            if (g < groups) GBODY(2)
        }
    }
#pragma unroll
    for (int mk = LPR; mk < 64; mk <<= 1) {
#pragma unroll
        for (int k = 0; k < 8; ++k) acc[k] += __shfl_xor(acc[k], mk, 64);
    }
    uint4 sv = *((const uint4*)(Hs + (size_t)d * C) + cl);
    acc[0] += bf_lo(sv.x); acc[1] += bf_hi(sv.x);
    acc[2] += bf_lo(sv.y); acc[3] += bf_hi(sv.y);
    acc[4] += bf_lo(sv.z); acc[5] += bf_hi(sv.z);
    acc[6] += bf_lo(sv.w); acc[7] += bf_hi(sv.w);

    float dv = dinv[d];
    float4 b0 = *((const float4*)bias + cl * 2);
    float4 b1 = *((const float4*)bias + cl * 2 + 1);
    float r[8];
    r[0] = dv * acc[0] + b0.x; r[1] = dv * acc[1] + b0.y;
    r[2] = dv * acc[2] + b0.z; r[3] = dv * acc[3] + b0.w;
    r[4] = dv * acc[4] + b1.x; r[5] = dv * acc[5] + b1.y;
    r[6] = dv * acc[6] + b1.z; r[7] = dv * acc[7] + b1.w;
    if (relu) {
#pragma unroll
        for (int k = 0; k < 8; ++k) r[k] = fmaxf(r[k], 0.f);
    }
    if (slot == 0) {
        if constexpr (BOUT) {
            uint4 o;
            o.x = (unsigned)f2bf(r[0]) | ((unsigned)f2bf(r[1]) << 16);
            o.y = (unsigned)f2bf(r[2]) | ((unsigned)f2bf(r[3]) << 16);
            o.z = (unsigned)f2bf(r[4]) | ((unsigned)f2bf(r[5]) << 16);
            o.w = (unsigned)f2bf(r[6]) | ((unsigned)f2bf(r[7]) << 16);
            *(uint4*)((unsigned short*)outv + (size_t)d * C + cl * 8) = o;
        } else {
            float* o = (float*)outv + (size_t)d * C + cl * 8;
            *(float4*)o = make_float4(r[0], r[1], r[2], r[3]);
            *(float4*)(o + 4) = make_float4(r[4], r[5], r[6], r[7]);
        }
    }
}

// ---- driver ----------------------------------------------------------------

extern "C" void kernel_launch(void* const* d_in, const int* in_sizes, int n_in,
                              void* d_out, int out_size, void* d_ws, size_t ws_size,
                              hipStream_t stream) {
    const float* x  = (const float*)d_in[0];
    const int*   ei = (const int*)d_in[1];
    const float* W1 = (const float*)d_in[2];
    const float* b1 = (const float*)d_in[3];
    const float* W2 = (const float*)d_in[4];
    const float* b2 = (const float*)d_in[5];
    float* out = (float*)d_out;

    int N = in_sizes[0] / IN_C;
    int E = in_sizes[1] / 2;
    const int* src = ei;
    const int* dst = ei + E;
    int B = (N + NPB - 1) >> NPB_SH;
    int nblk = (E + B1_CHUNK - 1) / B1_CHUNK;

    // workspace ≈ 65.3 MB for N=100k, E=1.6M (round-7 proven scale + 48KB)
    char* ws = (char*)d_ws;
    size_t off = 0;
    int*   bhist  = (int*)(ws + off);   off += (size_t)B * 4;
    int*   bbase  = (int*)(ws + off);   off += (size_t)(B + 1) * 4;
    int*   bcur   = (int*)(ws + off);   off += (size_t)B * 4;
    float* dinv   = (float*)(ws + off); off += (size_t)N * 4;
    int*   rowptr = (int*)(ws + off);   off += (size_t)N * 4;
    int*   rowend = (int*)(ws + off);   off += (size_t)N * 4;
    off = (off + 15) & ~(size_t)15;
    int*   col    = (int*)(ws + off);   off += ((size_t)E + (size_t)B * PADSLACK + 64) * 4;
    off = (off + 15) & ~(size_t)15;
    unsigned short* H1  = (unsigned short*)(ws + off); off += (size_t)(N + 1) * HID_C * 2;
    off = (off + 15) & ~(size_t)15;
    unsigned short* AG1 = (unsigned short*)(ws + off); off += (size_t)N * HID_C * 2;
    off = (off + 15) & ~(size_t)15;
    unsigned short* Wt1 = (unsigned short*)(ws + off); off += (size_t)128 * 128 * 2;
    unsigned short* Wt2 = (unsigned short*)(ws + off); off += (size_t)128 * 64 * 2;
    unsigned short* H2 = H1;   // reuse; sentinel row N fits ((N+1)*64 <= (N+1)*128)

    hipMemsetAsync(bhist, 0, (size_t)B * 4, stream);

    wcvt_kernel<<<16, 256, 0, stream>>>(W1, Wt1, HID_C);
    wcvt_kernel<<<8, 256, 0, stream>>>(W2, Wt2, OUT_C);

    hist_kernel<<<nblk, 256, 0, stream>>>(dst, bhist, E, B);
    scan_bucket_kernel<<<1, 1024, 0, stream>>>(bhist, bbase, bcur, B);
    bucket_kernel<<<nblk, 256, 0, stream>>>(src, dst, bcur, col, E, B);
    csr_kernel<<<B, 256, 0, stream>>>(col, bbase, rowptr, rowend, dinv, N, E);

    int mblk = (N + 63) / 64;
    mm_mfma_kernel<HID_C, float><<<mblk, 256, 0, stream>>>(x, Wt1, dinv, H1, N);
    agg_kernel<HID_C, true><<<(N + 3) / 4, 256, 0, stream>>>(
        H1, b1, dinv, rowptr, rowend, col, AG1, N, 1);

    mm_mfma_kernel<OUT_C, unsigned short><<<mblk, 256, 0, stream>>>(AG1, Wt2, dinv, H2, N);
    agg_kernel<OUT_C, false><<<(N + 3) / 4, 256, 0, stream>>>(
        H2, b2, dinv, rowptr, rowend, col, out, N, 0);
}